// Round 7
// baseline (289.099 us; speedup 1.0000x reference)
//
#include <hip/hip_runtime.h>
#include <hip/hip_bf16.h>
#include <stdint.h>

typedef __bf16 bf16_8 __attribute__((ext_vector_type(8)));
typedef float f32_4 __attribute__((ext_vector_type(4)));
typedef short short4v __attribute__((ext_vector_type(4)));

static __device__ __forceinline__ unsigned short f2bf(float f) {
    union { float f; unsigned int u; } v; v.f = f;
    unsigned int u = v.u;
    unsigned int r = (u + 0x7fffu + ((u >> 16) & 1u)) >> 16;
    return (unsigned short)r;
}

static __device__ __forceinline__ unsigned int pack_bf16x2(float a, float b) {
    union { float f; unsigned int u; } ua, ub;
    ua.f = a; ub.f = b;
    return __builtin_amdgcn_perm(ub.u + 0x8000u, ua.u + 0x8000u, 0x07060302u);
}

// 16x16x16 bf16 MFMA; B-operand layout == 16x16x32 C-layout (S^T feeds PV).
static __device__ __forceinline__ f32_4 mfma_16x16x16_bf16(short4v a, short4v b, f32_4 c) {
#if __has_builtin(__builtin_amdgcn_mfma_f32_16x16x16bf16_1k)
    return __builtin_amdgcn_mfma_f32_16x16x16bf16_1k(a, b, c, 0, 0, 0);
#else
    asm volatile("v_mfma_f32_16x16x16_bf16 %0, %1, %2, %0"
                 : "+v"(c) : "v"(a), "v"(b));
    return c;
#endif
}

// async global -> LDS, 16 B per lane (lds dest = wave-uniform base + lane*16)
static __device__ __forceinline__ void gll16(const unsigned short* g, unsigned short* l) {
    __builtin_amdgcn_global_load_lds(
        (const __attribute__((address_space(1))) unsigned int*)g,
        (__attribute__((address_space(3))) unsigned int*)l, 16, 0, 0);
}

// ---------------- fused prep: cvt x + transpose both weight matrices -------
// blocks [0,8192): cvt x->bf16; [8192,8960): w_qkv T; [8960,9216): w_proj T
__global__ __launch_bounds__(256) void prep_kernel(
    const float* __restrict__ x, unsigned int* __restrict__ xbf,
    const float* __restrict__ w_qkv, unsigned short* __restrict__ wqkvt,
    const float* __restrict__ w_proj, unsigned short* __restrict__ wprojt) {
    __shared__ unsigned short tile[64][65];
    int bid = blockIdx.x;
    if (bid < 8192) {
        int i = bid * 256 + threadIdx.x;
        float4 f = ((const float4*)x)[i];
        uint2 o;
        o.x = pack_bf16x2(f.x, f.y);
        o.y = pack_bf16x2(f.z, f.w);
        ((uint2*)xbf)[i] = o;
        return;
    }
    const float* in; unsigned short* out; int N, bx, by;
    if (bid < 8960) {
        in = w_qkv; out = wqkvt; N = 3072;
        int t = bid - 8192; bx = t % 48; by = t / 48;
    } else {
        in = w_proj; out = wprojt; N = 1024;
        int t = bid - 8960; bx = t & 15; by = t >> 4;
    }
    const int K = 1024;
    int k0 = by * 64, n0 = bx * 64;
    int tc = threadIdx.x & 63, tr = threadIdx.x >> 6;
    for (int p = 0; p < 16; ++p) {
        int k = p * 4 + tr;
        tile[k][tc] = f2bf(in[(size_t)(k0 + k) * N + n0 + tc]);
    }
    __syncthreads();
    for (int p = 0; p < 16; ++p) {
        int n = p * 4 + tr;
        out[(size_t)(n0 + n) * K + k0 + tc] = tile[tc][n];
    }
}

// ---------------- QKV GEMM: BK=64, swizzled gll16 staging ------------------
// Q/K blocks compute C^T via swapped MFMA operands -> uint2 packed stores.
// V blocks compute C and store transposed [bh][d][t] via uint2.
// Swizzle: staging lane l loads global 16B-chunk ((l&7)^(l>>3)) of its row;
// readers xor chunk index with (row&7)=(l16&7). Bank-uniform, unpadded.
#define BK 64
#define QSCALE 0.1803368801111204f  // 0.125 * log2(e)

__global__ __launch_bounds__(256) void gemm_qkv(
    const unsigned short* __restrict__ A,
    const unsigned short* __restrict__ Bt,
    const float* __restrict__ bias,
    int M, int N, int K,
    unsigned short* __restrict__ q_out, unsigned short* __restrict__ k_out,
    unsigned short* __restrict__ v_out) {
    __shared__ __align__(16) unsigned short As[128 * BK];
    __shared__ __align__(16) unsigned short Bs[128 * BK];
    int tid = threadIdx.x;
    int wave = tid >> 6, lane = tid & 63;
    int wm = wave & 1, wn = wave >> 1;
    int quad = lane >> 4, l16 = lane & 15;
    int m0 = blockIdx.y * 128, n0 = blockIdx.x * 128;
    int which = n0 >> 10;  // 0=Q 1=K 2=V

    f32_4 acc[4][4] = {};

    int srow = lane >> 3;                  // 0..7
    int scs = ((lane & 7) ^ srow) * 8;     // swizzled chunk elem offset
    const unsigned short* Ag = A + (size_t)(m0 + wave * 32 + srow) * K + scs;
    const unsigned short* Bg = Bt + (size_t)(n0 + wave * 32 + srow) * K + scs;
    unsigned short* Asl = As + wave * 32 * BK;
    unsigned short* Bsl = Bs + wave * 32 * BK;
    int sx = l16 & 7;

    for (int kt = 0; kt < K; kt += BK) {
        for (int p = 0; p < 4; ++p) {
            gll16(Ag + kt + (size_t)(8 * p) * K, Asl + p * 8 * BK);
            gll16(Bg + kt + (size_t)(8 * p) * K, Bsl + p * 8 * BK);
        }
        __syncthreads();
        bf16_8 af[4][2], bfr[4][2];
        for (int i = 0; i < 4; ++i)
            for (int ks = 0; ks < 2; ++ks)
                af[i][ks] = *(const bf16_8*)(As + (wm * 64 + i * 16 + l16) * BK +
                                             ((unsigned)((ks * 4 + quad) ^ sx)) * 8);
        for (int j = 0; j < 4; ++j)
            for (int ks = 0; ks < 2; ++ks)
                bfr[j][ks] = *(const bf16_8*)(Bs + (wn * 64 + j * 16 + l16) * BK +
                                              ((unsigned)((ks * 4 + quad) ^ sx)) * 8);
        if (which < 2) {
            for (int i = 0; i < 4; ++i)
                for (int j = 0; j < 4; ++j) {
                    acc[i][j] = __builtin_amdgcn_mfma_f32_16x16x32_bf16(bfr[j][0], af[i][0], acc[i][j], 0, 0, 0);
                    acc[i][j] = __builtin_amdgcn_mfma_f32_16x16x32_bf16(bfr[j][1], af[i][1], acc[i][j], 0, 0, 0);
                }
        } else {
            for (int i = 0; i < 4; ++i)
                for (int j = 0; j < 4; ++j) {
                    acc[i][j] = __builtin_amdgcn_mfma_f32_16x16x32_bf16(af[i][0], bfr[j][0], acc[i][j], 0, 0, 0);
                    acc[i][j] = __builtin_amdgcn_mfma_f32_16x16x32_bf16(af[i][1], bfr[j][1], acc[i][j], 0, 0, 0);
                }
        }
        __syncthreads();
    }

    int b = m0 >> 11;
    int tbase = (m0 & 2047) + wm * 64;
    int nw0 = n0 + wn * 64;
    if (which < 2) {
        unsigned short* dst = which == 0 ? q_out : k_out;
        float scale = which == 0 ? QSCALE : 1.0f;
        int h0 = ((n0 & 1023) >> 6) + wn;
        size_t base = ((size_t)((b << 4) + h0) * 2048) * 64;
        for (int j = 0; j < 4; ++j) {
            float4 b4 = *(const float4*)(bias + nw0 + j * 16 + quad * 4);
            int d0 = j * 16 + quad * 4;
            for (int i = 0; i < 4; ++i) {
                int t = tbase + i * 16 + l16;
                uint2 pk;
                pk.x = pack_bf16x2((acc[i][j][0] + b4.x) * scale,
                                   (acc[i][j][1] + b4.y) * scale);
                pk.y = pack_bf16x2((acc[i][j][2] + b4.z) * scale,
                                   (acc[i][j][3] + b4.w) * scale);
                *(uint2*)(dst + base + (size_t)t * 64 + d0) = pk;
            }
        }
    } else {
        for (int j = 0; j < 4; ++j) {
            int n = nw0 + j * 16 + l16;
            int c = n & 1023, h = c >> 6, d = c & 63;
            float bs = bias[n];
            size_t base = ((size_t)((b << 4) + h) * 64 + d) * 2048;
            for (int i = 0; i < 4; ++i) {
                int t0 = tbase + i * 16 + quad * 4;
                uint2 pk;
                pk.x = pack_bf16x2(acc[i][j][0] + bs, acc[i][j][1] + bs);
                pk.y = pack_bf16x2(acc[i][j][2] + bs, acc[i][j][3] + bs);
                *(uint2*)(v_out + base + t0) = pk;
            }
        }
    }
}

// ---------------- proj GEMM: BK=64, swizzled staging, BM=128 BN=64 ---------
__global__ __launch_bounds__(256) void gemm_proj(
    const unsigned short* __restrict__ A,
    const unsigned short* __restrict__ Bt,
    const float* __restrict__ bias,
    int M, int N, int K, float* __restrict__ outf) {
    __shared__ __align__(16) unsigned short As[128 * BK];
    __shared__ __align__(16) unsigned short Bs[64 * BK];
    int tid = threadIdx.x;
    int wave = tid >> 6, lane = tid & 63;
    int wm = wave & 1, wn = wave >> 1;  // wn 0..1
    int quad = lane >> 4, l16 = lane & 15;
    int m0 = blockIdx.y * 128, n0 = blockIdx.x * 64;

    f32_4 acc[4][2] = {};

    int srow = lane >> 3;
    int scs = ((lane & 7) ^ srow) * 8;
    const unsigned short* Ag = A + (size_t)(m0 + wave * 32 + srow) * K + scs;
    const unsigned short* Bg = Bt + (size_t)(n0 + wave * 16 + srow) * K + scs;
    unsigned short* Asl = As + wave * 32 * BK;
    unsigned short* Bsl = Bs + wave * 16 * BK;
    int sx = l16 & 7;

    for (int kt = 0; kt < K; kt += BK) {
        for (int p = 0; p < 4; ++p)
            gll16(Ag + kt + (size_t)(8 * p) * K, Asl + p * 8 * BK);
        for (int p = 0; p < 2; ++p)
            gll16(Bg + kt + (size_t)(8 * p) * K, Bsl + p * 8 * BK);
        __syncthreads();
        bf16_8 af[4][2], bfr[2][2];
        for (int i = 0; i < 4; ++i)
            for (int ks = 0; ks < 2; ++ks)
                af[i][ks] = *(const bf16_8*)(As + (wm * 64 + i * 16 + l16) * BK +
                                             ((unsigned)((ks * 4 + quad) ^ sx)) * 8);
        for (int j = 0; j < 2; ++j)
            for (int ks = 0; ks < 2; ++ks)
                bfr[j][ks] = *(const bf16_8*)(Bs + (wn * 32 + j * 16 + l16) * BK +
                                              ((unsigned)((ks * 4 + quad) ^ sx)) * 8);
        for (int i = 0; i < 4; ++i)
            for (int j = 0; j < 2; ++j) {
                acc[i][j] = __builtin_amdgcn_mfma_f32_16x16x32_bf16(af[i][0], bfr[j][0], acc[i][j], 0, 0, 0);
                acc[i][j] = __builtin_amdgcn_mfma_f32_16x16x32_bf16(af[i][1], bfr[j][1], acc[i][j], 0, 0, 0);
            }
        __syncthreads();
    }

    for (int j = 0; j < 2; ++j) {
        int n = n0 + wn * 32 + j * 16 + l16;
        float bs = bias[n];
        for (int i = 0; i < 4; ++i) {
            int m = m0 + wm * 64 + i * 16 + quad * 4;
            for (int r = 0; r < 4; ++r)
                outf[(size_t)(m + r) * N + n] = acc[i][j][r] + bs;
        }
    }
}

// ---------------- flash attention: 2 q-tiles share one K/V staging pass ----
// Q/K: [B*H][T][64] bf16 (Q pre-scaled 0.125*log2e). Vt: [B*H][64][T].
// Block (bh, y): tiles qtA=31-y (64 rows) and qtB=y share the k-loop
// (kt<=qtA; tile B active while kt<=qtB) -> 33 compute-steps/block, balanced.
// Staging via swizzled async gll16 into unpadded [64][64] double buffers.
// No-max softmax (bounded inputs); PV via 16x16x16 direct-B.
__global__ __launch_bounds__(256, 4) void attn_kernel(
    const unsigned short* __restrict__ Q, const unsigned short* __restrict__ Kb,
    const unsigned short* __restrict__ Vt, unsigned short* __restrict__ Y,
    int T) {
    __shared__ __align__(16) unsigned short KsB[2][64 * 64];
    __shared__ __align__(16) unsigned short VtsB[2][64 * 64];

    int tid = threadIdx.x;
    int wave = tid >> 6, lane = tid & 63;
    int quad = lane >> 4, l16 = lane & 15;
    int bh = blockIdx.x;
    int b = bh >> 4, h = bh & 15;
    int y = blockIdx.y;
    int qtA = 31 - y, qtB = y;
    int qwA = qtA * 64 + wave * 16;
    int qwB = qtB * 64 + wave * 16;

    int srow = lane >> 3;
    int scs = ((lane & 7) ^ srow) * 8;
    int sx = l16 & 7;

    // Q fragments
    bf16_8 qaA[2], qaB[2];
    for (int ks = 0; ks < 2; ++ks) {
        qaA[ks] = *(const bf16_8*)(Q + ((size_t)bh * T + qwA + l16) * 64 + ks * 32 + quad * 8);
        qaB[ks] = *(const bf16_8*)(Q + ((size_t)bh * T + qwB + l16) * 64 + ks * 32 + quad * 8);
    }

    f32_4 oA[4] = {}, oB[4] = {};
    float lsA = 0.0f, lsB = 0.0f;

    int nkt = qtA + 1;

    // stage tile 0 into buffer 0 (async)
    for (int p = 0; p < 2; ++p) {
        int row = wave * 16 + p * 8;
        gll16(Kb + ((size_t)bh * T + row + srow) * 64 + scs, &KsB[0][row * 64]);
        gll16(Vt + ((size_t)bh * 64 + row + srow) * (size_t)T + scs, &VtsB[0][row * 64]);
    }
    __syncthreads();

    for (int kt = 0; kt < nkt; ++kt) {
        int cur = kt & 1;
        int kb = kt * 64;
        if (kt + 1 < nkt) {
            int kb2 = kb + 64, nxt = cur ^ 1;
            for (int p = 0; p < 2; ++p) {
                int row = wave * 16 + p * 8;
                gll16(Kb + ((size_t)bh * T + kb2 + row + srow) * 64 + scs, &KsB[nxt][row * 64]);
                gll16(Vt + ((size_t)bh * 64 + row + srow) * (size_t)T + kb2 + scs, &VtsB[nxt][row * 64]);
            }
        }
        const unsigned short* KsC = KsB[cur];
        const unsigned short* VtsC = VtsB[cur];
        bool doB = (kt <= qtB);

        // S^T = K @ Q^T for both tiles, sharing the K fragment reads
        f32_4 sA[4] = {}, sB[4] = {};
        for (int kf = 0; kf < 4; ++kf) {
            bf16_8 k0 = *(const bf16_8*)(KsC + (kf * 16 + l16) * 64 + ((unsigned)(quad ^ sx)) * 8);
            bf16_8 k1 = *(const bf16_8*)(KsC + (kf * 16 + l16) * 64 + ((unsigned)((4 + quad) ^ sx)) * 8);
            sA[kf] = __builtin_amdgcn_mfma_f32_16x16x32_bf16(k0, qaA[0], sA[kf], 0, 0, 0);
            sA[kf] = __builtin_amdgcn_mfma_f32_16x16x32_bf16(k1, qaA[1], sA[kf], 0, 0, 0);
            if (doB) {
                sB[kf] = __builtin_amdgcn_mfma_f32_16x16x32_bf16(k0, qaB[0], sB[kf], 0, 0, 0);
                sB[kf] = __builtin_amdgcn_mfma_f32_16x16x32_bf16(k1, qaB[1], sB[kf], 0, 0, 0);
            }
        }

        // causal mask (diagonal tiles only)
        if (kt == qtA) {
            int q = qwA + l16;
            for (int kf = 0; kf < 4; ++kf) {
                int kk = kb + kf * 16 + quad * 4;
                for (int r = 0; r < 4; ++r)
                    if (kk + r > q) sA[kf][r] = -1e30f;
            }
        }
        if (kt == qtB) {
            int q = qwB + l16;
            for (int kf = 0; kf < 4; ++kf) {
                int kk = kb + kf * 16 + quad * 4;
                for (int r = 0; r < 4; ++r)
                    if (kk + r > q) sB[kf][r] = -1e30f;
            }
        }

        // no-max softmax + in-register pack to PV B-operands
        short4v pbA[4], pbB[4];
        {
            float rs = 0.0f;
            for (int kf = 0; kf < 4; ++kf) {
                f32_4 p;
                for (int r = 0; r < 4; ++r) { p[r] = __builtin_amdgcn_exp2f(sA[kf][r]); rs += p[r]; }
                union { unsigned int u[2]; short4v s4; } pu;
                pu.u[0] = pack_bf16x2(p[0], p[1]);
                pu.u[1] = pack_bf16x2(p[2], p[3]);
                pbA[kf] = pu.s4;
            }
            rs += __shfl_xor(rs, 16);
            rs += __shfl_xor(rs, 32);
            lsA += rs;
        }
        if (doB) {
            float rs = 0.0f;
            for (int kf = 0; kf < 4; ++kf) {
                f32_4 p;
                for (int r = 0; r < 4; ++r) { p[r] = __builtin_amdgcn_exp2f(sB[kf][r]); rs += p[r]; }
                union { unsigned int u[2]; short4v s4; } pu;
                pu.u[0] = pack_bf16x2(p[0], p[1]);
                pu.u[1] = pack_bf16x2(p[2], p[3]);
                pbB[kf] = pu.s4;
            }
            rs += __shfl_xor(rs, 16);
            rs += __shfl_xor(rs, 32);
            lsB += rs;
        }

        // PV: shared V^T fragment reads feed both tiles
        for (int kf = 0; kf < 4; ++kf) {
            unsigned voff = ((unsigned)((2 * kf + (quad >> 1)) ^ sx)) * 8 + (quad & 1) * 4;
            for (int df = 0; df < 4; ++df) {
                short4v va = *(const short4v*)(VtsC + (df * 16 + l16) * 64 + voff);
                oA[df] = mfma_16x16x16_bf16(va, pbA[kf], oA[df]);
                if (doB) oB[df] = mfma_16x16x16_bf16(va, pbB[kf], oB[df]);
            }
        }
        __syncthreads();
    }

    // epilogue: normalize, pack, direct global uint2 stores (both tiles)
    {
        float inv = 1.0f / lsA;
        unsigned short* yp = Y + ((size_t)b * T + qwA + l16) * 1024 + h * 64 + quad * 4;
        for (int df = 0; df < 4; ++df) {
            uint2 pk;
            pk.x = pack_bf16x2(oA[df][0] * inv, oA[df][1] * inv);
            pk.y = pack_bf16x2(oA[df][2] * inv, oA[df][3] * inv);
            *(uint2*)(yp + df * 16) = pk;
        }
    }
    {
        float inv = 1.0f / lsB;
        unsigned short* yp = Y + ((size_t)b * T + qwB + l16) * 1024 + h * 64 + quad * 4;
        for (int df = 0; df < 4; ++df) {
            uint2 pk;
            pk.x = pack_bf16x2(oB[df][0] * inv, oB[df][1] * inv);
            pk.y = pack_bf16x2(oB[df][2] * inv, oB[df][3] * inv);
            *(uint2*)(yp + df * 16) = pk;
        }
    }
}

extern "C" void kernel_launch(void* const* d_in, const int* in_sizes, int n_in,
                              void* d_out, int out_size, void* d_ws, size_t ws_size,
                              hipStream_t stream) {
    const float* x = (const float*)d_in[0];
    const float* w_qkv = (const float*)d_in[1];
    const float* b_qkv = (const float*)d_in[2];
    const float* w_proj = (const float*)d_in[3];
    const float* b_proj = (const float*)d_in[4];
    float* out = (float*)d_out;

    // workspace carve (ushort elements)
    unsigned short* xbf = (unsigned short*)d_ws;        // 8192*1024
    unsigned short* wqkvt = xbf + 8388608;              // 3072*1024
    unsigned short* wprojt = wqkvt + 3145728;           // 1024*1024
    unsigned short* Qb = wprojt + 1048576;              // 64*2048*64
    unsigned short* Kb = Qb + 8388608;
    unsigned short* Vtb = Kb + 8388608;                 // V transposed [bh][d][t]
    unsigned short* Yb = Vtb + 8388608;

    hipLaunchKernelGGL(prep_kernel, dim3(9216), dim3(256), 0, stream,
                       x, (unsigned int*)xbf, w_qkv, wqkvt, w_proj, wprojt);
    hipLaunchKernelGGL(gemm_qkv, dim3(24, 64), dim3(256), 0, stream,
                       xbf, wqkvt, b_qkv, 8192, 3072, 1024,
                       Qb, Kb, Vtb);
    hipLaunchKernelGGL(attn_kernel, dim3(64, 16), dim3(256), 0, stream,
                       Qb, Kb, Vtb, Yb, 2048);
    hipLaunchKernelGGL(gemm_proj, dim3(16, 64), dim3(256), 0, stream,
                       Yb, wprojt, b_proj, 8192, 1024, 1024, out);
}

// Round 8
// 262.171 us; speedup vs baseline: 1.1027x; 1.1027x over previous
//
#include <hip/hip_runtime.h>
#include <hip/hip_bf16.h>
#include <stdint.h>

typedef __bf16 bf16_8 __attribute__((ext_vector_type(8)));
typedef float f32_4 __attribute__((ext_vector_type(4)));
typedef short short4v __attribute__((ext_vector_type(4)));

static __device__ __forceinline__ unsigned short f2bf(float f) {
    union { float f; unsigned int u; } v; v.f = f;
    unsigned int u = v.u;
    unsigned int r = (u + 0x7fffu + ((u >> 16) & 1u)) >> 16;
    return (unsigned short)r;
}

static __device__ __forceinline__ unsigned int pack_bf16x2(float a, float b) {
    union { float f; unsigned int u; } ua, ub;
    ua.f = a; ub.f = b;
    return __builtin_amdgcn_perm(ub.u + 0x8000u, ua.u + 0x8000u, 0x07060302u);
}

// 16x16x16 bf16 MFMA; B-operand layout == 16x16x32 C-layout (S^T feeds PV).
static __device__ __forceinline__ f32_4 mfma_16x16x16_bf16(short4v a, short4v b, f32_4 c) {
#if __has_builtin(__builtin_amdgcn_mfma_f32_16x16x16bf16_1k)
    return __builtin_amdgcn_mfma_f32_16x16x16bf16_1k(a, b, c, 0, 0, 0);
#else
    asm volatile("v_mfma_f32_16x16x16_bf16 %0, %1, %2, %0"
                 : "+v"(c) : "v"(a), "v"(b));
    return c;
#endif
}

// async global -> LDS, 16 B per lane (lds dest = wave-uniform base + lane*16)
static __device__ __forceinline__ void gll16(const unsigned short* g, unsigned short* l) {
    __builtin_amdgcn_global_load_lds(
        (const __attribute__((address_space(1))) unsigned int*)g,
        (__attribute__((address_space(3))) unsigned int*)l, 16, 0, 0);
}

// ---------------- fused prep: cvt x + transpose both weight matrices -------
__global__ __launch_bounds__(256) void prep_kernel(
    const float* __restrict__ x, unsigned int* __restrict__ xbf,
    const float* __restrict__ w_qkv, unsigned short* __restrict__ wqkvt,
    const float* __restrict__ w_proj, unsigned short* __restrict__ wprojt) {
    __shared__ unsigned short tile[64][65];
    int bid = blockIdx.x;
    if (bid < 8192) {
        int i = bid * 256 + threadIdx.x;
        float4 f = ((const float4*)x)[i];
        uint2 o;
        o.x = pack_bf16x2(f.x, f.y);
        o.y = pack_bf16x2(f.z, f.w);
        ((uint2*)xbf)[i] = o;
        return;
    }
    const float* in; unsigned short* out; int N, bx, by;
    if (bid < 8960) {
        in = w_qkv; out = wqkvt; N = 3072;
        int t = bid - 8192; bx = t % 48; by = t / 48;
    } else {
        in = w_proj; out = wprojt; N = 1024;
        int t = bid - 8960; bx = t & 15; by = t >> 4;
    }
    const int K = 1024;
    int k0 = by * 64, n0 = bx * 64;
    int tc = threadIdx.x & 63, tr = threadIdx.x >> 6;
    for (int p = 0; p < 16; ++p) {
        int k = p * 4 + tr;
        tile[k][tc] = f2bf(in[(size_t)(k0 + k) * N + n0 + tc]);
    }
    __syncthreads();
    for (int p = 0; p < 16; ++p) {
        int n = p * 4 + tr;
        out[(size_t)(n0 + n) * K + k0 + tc] = tile[tc][n];
    }
}

// ---------------- QKV GEMM: BK=64, swizzled gll16 staging (unchanged r7) ---
#define BK 64
#define QSCALE 0.1803368801111204f  // 0.125 * log2(e)

__global__ __launch_bounds__(256) void gemm_qkv(
    const unsigned short* __restrict__ A,
    const unsigned short* __restrict__ Bt,
    const float* __restrict__ bias,
    int M, int N, int K,
    unsigned short* __restrict__ q_out, unsigned short* __restrict__ k_out,
    unsigned short* __restrict__ v_out) {
    __shared__ __align__(16) unsigned short As[128 * BK];
    __shared__ __align__(16) unsigned short Bs[128 * BK];
    int tid = threadIdx.x;
    int wave = tid >> 6, lane = tid & 63;
    int wm = wave & 1, wn = wave >> 1;
    int quad = lane >> 4, l16 = lane & 15;
    int m0 = blockIdx.y * 128, n0 = blockIdx.x * 128;
    int which = n0 >> 10;  // 0=Q 1=K 2=V

    f32_4 acc[4][4] = {};

    int srow = lane >> 3;                  // 0..7
    int scs = ((lane & 7) ^ srow) * 8;     // swizzled chunk elem offset
    const unsigned short* Ag = A + (size_t)(m0 + wave * 32 + srow) * K + scs;
    const unsigned short* Bg = Bt + (size_t)(n0 + wave * 32 + srow) * K + scs;
    unsigned short* Asl = As + wave * 32 * BK;
    unsigned short* Bsl = Bs + wave * 32 * BK;
    int sx = l16 & 7;

    for (int kt = 0; kt < K; kt += BK) {
        for (int p = 0; p < 4; ++p) {
            gll16(Ag + kt + (size_t)(8 * p) * K, Asl + p * 8 * BK);
            gll16(Bg + kt + (size_t)(8 * p) * K, Bsl + p * 8 * BK);
        }
        __syncthreads();
        bf16_8 af[4][2], bfr[4][2];
        for (int i = 0; i < 4; ++i)
            for (int ks = 0; ks < 2; ++ks)
                af[i][ks] = *(const bf16_8*)(As + (wm * 64 + i * 16 + l16) * BK +
                                             ((unsigned)((ks * 4 + quad) ^ sx)) * 8);
        for (int j = 0; j < 4; ++j)
            for (int ks = 0; ks < 2; ++ks)
                bfr[j][ks] = *(const bf16_8*)(Bs + (wn * 64 + j * 16 + l16) * BK +
                                              ((unsigned)((ks * 4 + quad) ^ sx)) * 8);
        if (which < 2) {
            for (int i = 0; i < 4; ++i)
                for (int j = 0; j < 4; ++j) {
                    acc[i][j] = __builtin_amdgcn_mfma_f32_16x16x32_bf16(bfr[j][0], af[i][0], acc[i][j], 0, 0, 0);
                    acc[i][j] = __builtin_amdgcn_mfma_f32_16x16x32_bf16(bfr[j][1], af[i][1], acc[i][j], 0, 0, 0);
                }
        } else {
            for (int i = 0; i < 4; ++i)
                for (int j = 0; j < 4; ++j) {
                    acc[i][j] = __builtin_amdgcn_mfma_f32_16x16x32_bf16(af[i][0], bfr[j][0], acc[i][j], 0, 0, 0);
                    acc[i][j] = __builtin_amdgcn_mfma_f32_16x16x32_bf16(af[i][1], bfr[j][1], acc[i][j], 0, 0, 0);
                }
        }
        __syncthreads();
    }

    int b = m0 >> 11;
    int tbase = (m0 & 2047) + wm * 64;
    int nw0 = n0 + wn * 64;
    if (which < 2) {
        unsigned short* dst = which == 0 ? q_out : k_out;
        float scale = which == 0 ? QSCALE : 1.0f;
        int h0 = ((n0 & 1023) >> 6) + wn;
        size_t base = ((size_t)((b << 4) + h0) * 2048) * 64;
        for (int j = 0; j < 4; ++j) {
            float4 b4 = *(const float4*)(bias + nw0 + j * 16 + quad * 4);
            int d0 = j * 16 + quad * 4;
            for (int i = 0; i < 4; ++i) {
                int t = tbase + i * 16 + l16;
                uint2 pk;
                pk.x = pack_bf16x2((acc[i][j][0] + b4.x) * scale,
                                   (acc[i][j][1] + b4.y) * scale);
                pk.y = pack_bf16x2((acc[i][j][2] + b4.z) * scale,
                                   (acc[i][j][3] + b4.w) * scale);
                *(uint2*)(dst + base + (size_t)t * 64 + d0) = pk;
            }
        }
    } else {
        for (int j = 0; j < 4; ++j) {
            int n = nw0 + j * 16 + l16;
            int c = n & 1023, h = c >> 6, d = c & 63;
            float bs = bias[n];
            size_t base = ((size_t)((b << 4) + h) * 64 + d) * 2048;
            for (int i = 0; i < 4; ++i) {
                int t0 = tbase + i * 16 + quad * 4;
                uint2 pk;
                pk.x = pack_bf16x2(acc[i][j][0] + bs, acc[i][j][1] + bs);
                pk.y = pack_bf16x2(acc[i][j][2] + bs, acc[i][j][3] + bs);
                *(uint2*)(v_out + base + t0) = pk;
            }
        }
    }
}

// ---------------- proj GEMM: BM=128 BN=128 BK=64, swizzled staging ---------
__global__ __launch_bounds__(256) void gemm_proj(
    const unsigned short* __restrict__ A,
    const unsigned short* __restrict__ Bt,
    const float* __restrict__ bias,
    int M, int N, int K, float* __restrict__ outf) {
    __shared__ __align__(16) unsigned short As[128 * BK];
    __shared__ __align__(16) unsigned short Bs[128 * BK];
    int tid = threadIdx.x;
    int wave = tid >> 6, lane = tid & 63;
    int wm = wave & 1, wn = wave >> 1;
    int quad = lane >> 4, l16 = lane & 15;
    int m0 = blockIdx.y * 128, n0 = blockIdx.x * 128;

    f32_4 acc[4][4] = {};

    int srow = lane >> 3;
    int scs = ((lane & 7) ^ srow) * 8;
    const unsigned short* Ag = A + (size_t)(m0 + wave * 32 + srow) * K + scs;
    const unsigned short* Bg = Bt + (size_t)(n0 + wave * 32 + srow) * K + scs;
    unsigned short* Asl = As + wave * 32 * BK;
    unsigned short* Bsl = Bs + wave * 32 * BK;
    int sx = l16 & 7;

    for (int kt = 0; kt < K; kt += BK) {
        for (int p = 0; p < 4; ++p) {
            gll16(Ag + kt + (size_t)(8 * p) * K, Asl + p * 8 * BK);
            gll16(Bg + kt + (size_t)(8 * p) * K, Bsl + p * 8 * BK);
        }
        __syncthreads();
        bf16_8 af[4][2], bfr[4][2];
        for (int i = 0; i < 4; ++i)
            for (int ks = 0; ks < 2; ++ks)
                af[i][ks] = *(const bf16_8*)(As + (wm * 64 + i * 16 + l16) * BK +
                                             ((unsigned)((ks * 4 + quad) ^ sx)) * 8);
        for (int j = 0; j < 4; ++j)
            for (int ks = 0; ks < 2; ++ks)
                bfr[j][ks] = *(const bf16_8*)(Bs + (wn * 64 + j * 16 + l16) * BK +
                                              ((unsigned)((ks * 4 + quad) ^ sx)) * 8);
        for (int i = 0; i < 4; ++i)
            for (int j = 0; j < 4; ++j) {
                acc[i][j] = __builtin_amdgcn_mfma_f32_16x16x32_bf16(af[i][0], bfr[j][0], acc[i][j], 0, 0, 0);
                acc[i][j] = __builtin_amdgcn_mfma_f32_16x16x32_bf16(af[i][1], bfr[j][1], acc[i][j], 0, 0, 0);
            }
        __syncthreads();
    }

    for (int j = 0; j < 4; ++j) {
        int n = n0 + wn * 64 + j * 16 + l16;
        float bs = bias[n];
        for (int i = 0; i < 4; ++i) {
            int m = m0 + wm * 64 + i * 16 + quad * 4;
            for (int r = 0; r < 4; ++r)
                outf[(size_t)(m + r) * N + n] = acc[i][j][r] + bs;
        }
    }
}

// ---------------- flash attention: single 64-row tile/block, 5 blocks/CU ---
// Q/K: [B*H][T][64] bf16 (Q pre-scaled 0.125*log2e). Vt: [B*H][64][T].
// grid (64 bh, 32 tiles): blockIdx.x=bh keeps all 32 blocks of a head on one
// XCD (id%8 = bh%8). qt = 31-y -> heavy blocks dispatch first; 2048 blocks
// backfill the causal imbalance at 5 blocks/CU (LDS 32KB, launch_bounds 5).
// No-max softmax (bounded inputs); lsum via ones-MFMA (no shuffles);
// PV via 16x16x16 direct-B (S^T C-layout == B-operand layout).
__global__ __launch_bounds__(256, 5) void attn_kernel(
    const unsigned short* __restrict__ Q, const unsigned short* __restrict__ Kb,
    const unsigned short* __restrict__ Vt, unsigned short* __restrict__ Y,
    int T) {
    __shared__ __align__(16) unsigned short KsB[2][64 * 64];
    __shared__ __align__(16) unsigned short VtsB[2][64 * 64];

    int tid = threadIdx.x;
    int wave = tid >> 6, lane = tid & 63;
    int quad = lane >> 4, l16 = lane & 15;
    int bh = blockIdx.x;
    int b = bh >> 4, h = bh & 15;
    int qt = 31 - blockIdx.y;
    int qw = qt * 64 + wave * 16;
    int nkt = qt + 1;

    int srow = lane >> 3;
    int scs = ((lane & 7) ^ srow) * 8;
    int sx = l16 & 7;

    // Q fragments: q = l16 (B-operand compatible), d = ks*32+quad*8
    bf16_8 qa[2];
    for (int ks = 0; ks < 2; ++ks)
        qa[ks] = *(const bf16_8*)(Q + ((size_t)bh * T + qw + l16) * 64 + ks * 32 + quad * 8);

    f32_4 o[4] = {};    // [df]: d = df*16+quad*4+r, q = l16
    f32_4 osum = {};    // lsum via ones-MFMA: all 4 regs identical
    short4v vones;
    { unsigned short one = 0x3F80;
      vones[0] = (short)one; vones[1] = (short)one; vones[2] = (short)one; vones[3] = (short)one; }

    // stage tile 0 into buffer 0 (async, swizzled)
    for (int p = 0; p < 2; ++p) {
        int row = wave * 16 + p * 8;
        gll16(Kb + ((size_t)bh * T + row + srow) * 64 + scs, &KsB[0][row * 64]);
        gll16(Vt + ((size_t)bh * 64 + row + srow) * (size_t)T + scs, &VtsB[0][row * 64]);
    }
    __syncthreads();

    for (int kt = 0; kt < nkt; ++kt) {
        int cur = kt & 1;
        int kb = kt * 64;
        if (kt + 1 < nkt) {
            int kb2 = kb + 64, nxt = cur ^ 1;
            for (int p = 0; p < 2; ++p) {
                int row = wave * 16 + p * 8;
                gll16(Kb + ((size_t)bh * T + kb2 + row + srow) * 64 + scs, &KsB[nxt][row * 64]);
                gll16(Vt + ((size_t)bh * 64 + row + srow) * (size_t)T + kb2 + scs, &VtsB[nxt][row * 64]);
            }
        }
        const unsigned short* KsC = KsB[cur];
        const unsigned short* VtsC = VtsB[cur];

        // S^T = K @ Q^T : lane holds (k = kf*16+quad*4+r, q = l16)
        f32_4 s[4] = {};
        for (int kf = 0; kf < 4; ++kf) {
            bf16_8 k0 = *(const bf16_8*)(KsC + (kf * 16 + l16) * 64 + ((unsigned)(quad ^ sx)) * 8);
            bf16_8 k1 = *(const bf16_8*)(KsC + (kf * 16 + l16) * 64 + ((unsigned)((4 + quad) ^ sx)) * 8);
            s[kf] = __builtin_amdgcn_mfma_f32_16x16x32_bf16(k0, qa[0], s[kf], 0, 0, 0);
            s[kf] = __builtin_amdgcn_mfma_f32_16x16x32_bf16(k1, qa[1], s[kf], 0, 0, 0);
        }

        // causal mask (diagonal tile only)
        if (kt == qt) {
            int q = qw + l16;
            for (int kf = 0; kf < 4; ++kf) {
                int kk = kb + kf * 16 + quad * 4;
                for (int r = 0; r < 4; ++r)
                    if (kk + r > q) s[kf][r] = -1e30f;
            }
        }

        // no-max softmax: p = 2^s, packed in-register to PV B-operands
        short4v pb[4];
        for (int kf = 0; kf < 4; ++kf) {
            float p0 = __builtin_amdgcn_exp2f(s[kf][0]);
            float p1 = __builtin_amdgcn_exp2f(s[kf][1]);
            float p2 = __builtin_amdgcn_exp2f(s[kf][2]);
            float p3 = __builtin_amdgcn_exp2f(s[kf][3]);
            union { unsigned int u[2]; short4v s4; } pu;
            pu.u[0] = pack_bf16x2(p0, p1);
            pu.u[1] = pack_bf16x2(p2, p3);
            pb[kf] = pu.s4;
        }

        // PV + lsum: o[df] += V^T@P^T ; osum += 1@P^T (rowsum, no shuffles)
        for (int kf = 0; kf < 4; ++kf) {
            osum = mfma_16x16x16_bf16(vones, pb[kf], osum);
            unsigned voff = ((unsigned)((2 * kf + (quad >> 1)) ^ sx)) * 8 + (quad & 1) * 4;
            for (int df = 0; df < 4; ++df) {
                short4v va = *(const short4v*)(VtsC + (df * 16 + l16) * 64 + voff);
                o[df] = mfma_16x16x16_bf16(va, pb[kf], o[df]);
            }
        }
        __syncthreads();
    }

    // epilogue: normalize by osum (all 4 regs identical), packed stores
    float inv = 1.0f / osum[0];
    unsigned short* yp = Y + ((size_t)b * T + qw + l16) * 1024 + h * 64 + quad * 4;
    for (int df = 0; df < 4; ++df) {
        uint2 pk;
        pk.x = pack_bf16x2(o[df][0] * inv, o[df][1] * inv);
        pk.y = pack_bf16x2(o[df][2] * inv, o[df][3] * inv);
        *(uint2*)(yp + df * 16) = pk;
    }
}

extern "C" void kernel_launch(void* const* d_in, const int* in_sizes, int n_in,
                              void* d_out, int out_size, void* d_ws, size_t ws_size,
                              hipStream_t stream) {
    const float* x = (const float*)d_in[0];
    const float* w_qkv = (const float*)d_in[1];
    const float* b_qkv = (const float*)d_in[2];
    const float* w_proj = (const float*)d_in[3];
    const float* b_proj = (const float*)d_in[4];
    float* out = (float*)d_out;

    // workspace carve (ushort elements)
    unsigned short* xbf = (unsigned short*)d_ws;        // 8192*1024
    unsigned short* wqkvt = xbf + 8388608;              // 3072*1024
    unsigned short* wprojt = wqkvt + 3145728;           // 1024*1024
    unsigned short* Qb = wprojt + 1048576;              // 64*2048*64
    unsigned short* Kb = Qb + 8388608;
    unsigned short* Vtb = Kb + 8388608;                 // V transposed [bh][d][t]
    unsigned short* Yb = Vtb + 8388608;

    hipLaunchKernelGGL(prep_kernel, dim3(9216), dim3(256), 0, stream,
                       x, (unsigned int*)xbf, w_qkv, wqkvt, w_proj, wprojt);
    hipLaunchKernelGGL(gemm_qkv, dim3(24, 64), dim3(256), 0, stream,
                       xbf, wqkvt, b_qkv, 8192, 3072, 1024,
                       Qb, Kb, Vtb);
    hipLaunchKernelGGL(attn_kernel, dim3(64, 32), dim3(256), 0, stream,
                       Qb, Kb, Vtb, Yb, 2048);
    hipLaunchKernelGGL(gemm_proj, dim3(8, 64), dim3(256), 0, stream,
                       Yb, wprojt, b_proj, 8192, 1024, 1024, out);
}